// Round 1
// baseline (642.770 us; speedup 1.0000x reference)
//
#include <hip/hip_runtime.h>

// Bilinear 2x upsample, NHWC f32.
// in : (8, 256, 256, 64)  out : (8, 512, 512, 64)
// Memory-bound: 536 MB write + 134 MB read. One float4 (4 channels) per
// thread -> wave64 stores 1 KiB contiguous; 16 lanes cover one output pixel.

constexpr int B     = 8;
constexpr int IN_H  = 256;
constexpr int IN_W  = 256;
constexpr int OUT_H = 512;
constexpr int OUT_W = 512;
constexpr int C     = 64;
constexpr int C4    = C / 4;              // 16 float4 per pixel
constexpr int TOTAL = B * OUT_H * OUT_W * C4;  // 33,554,432 threads

__global__ __launch_bounds__(256) void
bilerp2x_kernel(const float4* __restrict__ in, float4* __restrict__ out) {
    int i = blockIdx.x * blockDim.x + threadIdx.x;   // < 2^25, int is fine

    int c4   = i & (C4 - 1);
    int pix  = i >> 4;                    // log2(C4)
    int ox   = pix & (OUT_W - 1);
    int rest = pix >> 9;                  // log2(OUT_W)
    int oy   = rest & (OUT_H - 1);
    int b    = rest >> 9;                 // log2(OUT_H)

    // src = max((o+0.5)*0.5 - 0.5, 0); exact in f32 (multiples of 0.25)
    float sy = fmaxf((oy + 0.5f) * 0.5f - 0.5f, 0.0f);
    float sx = fmaxf((ox + 0.5f) * 0.5f - 0.5f, 0.0f);
    int y0 = (int)sy;                     // trunc == floor (sy >= 0)
    int x0 = (int)sx;
    int y1 = min(y0 + 1, IN_H - 1);
    int x1 = min(x0 + 1, IN_W - 1);
    float dy = sy - (float)y0;
    float dx = sx - (float)x0;

    int row0 = (b * IN_H + y0) * IN_W;    // in units of pixels
    int row1 = (b * IN_H + y1) * IN_W;

    const float4 lt = in[(row0 + x0) * C4 + c4];
    const float4 rt = in[(row0 + x1) * C4 + c4];
    const float4 lb = in[(row1 + x0) * C4 + c4];
    const float4 rb = in[(row1 + x1) * C4 + c4];

    // two lerps: t = lt + dx*(rt-lt); bo = lb + dx*(rb-lb); o = t + dy*(bo-t)
    float4 t, bo, o;
    t.x = fmaf(dx, rt.x - lt.x, lt.x);
    t.y = fmaf(dx, rt.y - lt.y, lt.y);
    t.z = fmaf(dx, rt.z - lt.z, lt.z);
    t.w = fmaf(dx, rt.w - lt.w, lt.w);
    bo.x = fmaf(dx, rb.x - lb.x, lb.x);
    bo.y = fmaf(dx, rb.y - lb.y, lb.y);
    bo.z = fmaf(dx, rb.z - lb.z, lb.z);
    bo.w = fmaf(dx, rb.w - lb.w, lb.w);
    o.x = fmaf(dy, bo.x - t.x, t.x);
    o.y = fmaf(dy, bo.y - t.y, t.y);
    o.z = fmaf(dy, bo.z - t.z, t.z);
    o.w = fmaf(dy, bo.w - t.w, t.w);

    out[i] = o;
}

extern "C" void kernel_launch(void* const* d_in, const int* in_sizes, int n_in,
                              void* d_out, int out_size, void* d_ws, size_t ws_size,
                              hipStream_t stream) {
    (void)in_sizes; (void)n_in; (void)d_ws; (void)ws_size; (void)out_size;
    const float4* in  = (const float4*)d_in[0];
    float4*       out = (float4*)d_out;
    dim3 block(256);
    dim3 grid(TOTAL / 256);               // 131,072 blocks
    bilerp2x_kernel<<<grid, block, 0, stream>>>(in, out);
}